// Round 1
// baseline (169.742 us; speedup 1.0000x reference)
//
#include <hip/hip_runtime.h>
#include <math.h>

#define HAND_PARAM_DIM 32
#define MASK_THRESHOLD 0.5f
#define INF_DIST 1000000.0f
#define EPS 1e-8f
#define NROW 64        // B*S
#define HW_N 65536
#define NV 778
#define NMESH (2*NV)   // 1556
#define K_SEL 1024

// ---------------------------------------------------------------------------
// Kernel A: MANO mesh points. One block per (row, hand). 128 blocks x 256 thr.
// ---------------------------------------------------------------------------
__global__ void __launch_bounds__(256) mesh_kernel(
    const float* __restrict__ hp, const int* __restrict__ hv,
    const float* __restrict__ vtl, const float* __restrict__ vtr,
    const float* __restrict__ sdl, const float* __restrict__ sdr,
    const float* __restrict__ pdl, const float* __restrict__ pdr,
    float* __restrict__ meshX, float* __restrict__ meshY, float* __restrict__ meshZ)
{
    int blk  = blockIdx.x;
    int row  = blk >> 1;
    int hand = blk & 1;
    const float* p = hp + row * (2 * HAND_PARAM_DIM) + hand * HAND_PARAM_DIM;
    int valid = hv[row * 2 + hand];

    const float* vt = hand ? vtr : vtl;
    const float* sd = hand ? sdr : sdl;
    const float* pd = hand ? pdr : pdl;

    // per-hand scalars (computed redundantly by every thread; broadcast loads)
    float tx = p[0], ty = p[1], tz = p[2];
    float q0 = p[3], q1 = p[4], q2 = p[5], q3 = p[6];
    float qn = sqrtf(q0*q0 + q1*q1 + q2*q2 + q3*q3 + EPS);
    float inv = 1.0f / fmaxf(qn, EPS);
    q0 *= inv; q1 *= inv; q2 *= inv; q3 *= inv;
    float sgn = (q0 < 0.0f) ? -1.0f : 1.0f;
    q0 *= sgn; q1 *= sgn; q2 *= sgn; q3 *= sgn;
    float sin_half = sqrtf(q1*q1 + q2*q2 + q3*q3 + EPS);
    float w_safe = fminf(fmaxf(q0, -1.0f + EPS), 1.0f - EPS);
    float ang2 = 2.0f * atan2f(sin_half, w_safe);
    float factor = (sin_half < 1e-6f) ? 2.0f : ang2 / fmaxf(sin_half, EPS);
    float rx = q1 * factor, ry = q2 * factor, rz = q3 * factor;
    float ang = sqrtf(rx*rx + ry*ry + rz*rz + EPS);
    float iang = 1.0f / ang;
    float ax = rx * iang, ay = ry * iang, az = rz * iang;
    float c = cosf(ang), s = sinf(ang), omc = 1.0f - c;

    float pose[15], betas[10];
#pragma unroll
    for (int k = 0; k < 15; k++) pose[k] = p[7 + k];
#pragma unroll
    for (int k = 0; k < 10; k++) betas[k] = p[22 + k];

    for (int v = threadIdx.x; v < NV; v += blockDim.x) {
        float px = vt[v*3+0], py = vt[v*3+1], pz = vt[v*3+2];
        const float* sdv = sd + v * 30;   // (3,10) row-major
#pragma unroll
        for (int k = 0; k < 10; k++) {
            px = fmaf(sdv[k],      betas[k], px);
            py = fmaf(sdv[10 + k], betas[k], py);
            pz = fmaf(sdv[20 + k], betas[k], pz);
        }
        const float* pdv = pd + v * 45;   // (3,15) row-major
#pragma unroll
        for (int k = 0; k < 15; k++) {
            px = fmaf(pdv[k],      pose[k], px);
            py = fmaf(pdv[15 + k], pose[k], py);
            pz = fmaf(pdv[30 + k], pose[k], pz);
        }
        // rodrigues: pts*c + (k x pts)*s + k*(k.pts)*(1-c) + transl
        float cx = ay * pz - az * py;
        float cy = az * px - ax * pz;
        float cz = ax * py - ay * px;
        float kdv = ax * px + ay * py + az * pz;
        float ox = px * c + cx * s + ax * kdv * omc + tx;
        float oy = py * c + cy * s + ay * kdv * omc + ty;
        float oz = pz * c + cz * s + az * kdv * omc + tz;
        if (!valid) { ox = INF_DIST; oy = INF_DIST; oz = INF_DIST; }
        int o = row * NMESH + hand * NV + v;
        meshX[o] = ox; meshY[o] = oy; meshZ[o] = oz;
    }
}

// ---------------------------------------------------------------------------
// Kernel B: exact top-1024 per row via 3-phase radix select on float bits.
// One block per row, 1024 threads. Deterministic compaction via prefix scan.
// ---------------------------------------------------------------------------
__global__ void __launch_bounds__(1024) topk_kernel(
    const float* __restrict__ mask, const float* __restrict__ means,
    const int* __restrict__ hv,
    float* __restrict__ sampX, float* __restrict__ sampY, float* __restrict__ sampZ,
    int* __restrict__ cnt)
{
    __shared__ unsigned hist[4096];
    __shared__ unsigned scn[1024];
    __shared__ unsigned sb1, sr1, sb2, sr2, sT, sr3;
    __shared__ unsigned tiebuf[64];
    __shared__ unsigned ntie;

    int row = blockIdx.x;
    int t = threadIdx.x;

    int anyvalid = (hv[row * 2] != 0) || (hv[row * 2 + 1] != 0);
    if (!anyvalid) {            // uniform across block: safe early-out
        if (t == 0) cnt[row] = 0;
        return;
    }
    const float* m = mask + (size_t)row * HW_N;

    // ---- phase 1: 1024 bins on bits>>20 (mask in [0,1) -> bin <= 1015) ----
    hist[t] = 0;
    __syncthreads();
    for (int i = 0; i < 64; i++) {
        unsigned u = __float_as_uint(m[t + i * 1024]);
        unsigned b = u >> 20; if (b > 1023u) b = 1023u;
        atomicAdd(&hist[b], 1u);
    }
    __syncthreads();
    unsigned own = hist[t];
    scn[t] = own;
    __syncthreads();
    for (int off = 1; off < 1024; off <<= 1) {           // inclusive suffix scan
        unsigned v = (t + off < 1024) ? scn[t + off] : 0u;
        __syncthreads();
        scn[t] += v;
        __syncthreads();
    }
    {
        unsigned excl = (t < 1023) ? scn[t + 1] : 0u;
        if (excl < K_SEL && K_SEL <= scn[t]) { sb1 = (unsigned)t; sr1 = K_SEL - excl; }
    }
    __syncthreads();
    unsigned b1 = sb1, r1 = sr1;

    // ---- phase 2: 4096 bins on (bits>>8)&0xFFF among bin b1 ----
    hist[t] = 0; hist[t + 1024] = 0; hist[t + 2048] = 0; hist[t + 3072] = 0;
    __syncthreads();
    for (int i = 0; i < 64; i++) {
        unsigned u = __float_as_uint(m[t + i * 1024]);
        if ((u >> 20) == b1) atomicAdd(&hist[(u >> 8) & 0xFFFu], 1u);
    }
    __syncthreads();
    unsigned l0 = hist[t*4], l1 = hist[t*4+1], l2 = hist[t*4+2], l3 = hist[t*4+3];
    scn[t] = l0 + l1 + l2 + l3;
    __syncthreads();
    for (int off = 1; off < 1024; off <<= 1) {
        unsigned v = (t + off < 1024) ? scn[t + off] : 0u;
        __syncthreads();
        scn[t] += v;
        __syncthreads();
    }
    {
        unsigned excl = (t < 1023) ? scn[t + 1] : 0u;
        if (excl < r1 && r1 <= scn[t]) {
            unsigned loc[4] = { l0, l1, l2, l3 };
            unsigned acc = excl;
            for (int b = 3; b >= 0; b--) {
                if (acc + loc[b] >= r1) { sb2 = (unsigned)(t * 4 + b); sr2 = r1 - acc; break; }
                acc += loc[b];
            }
        }
    }
    __syncthreads();
    unsigned pref24 = (b1 << 12) | sb2;   // == bits>>8 of threshold
    unsigned r2 = sr2;

    // ---- phase 3: 256 bins on low byte among prefix pref24 ----
    if (t < 256) hist[t] = 0;
    __syncthreads();
    for (int i = 0; i < 64; i++) {
        unsigned u = __float_as_uint(m[t + i * 1024]);
        if ((u >> 8) == pref24) atomicAdd(&hist[u & 0xFFu], 1u);
    }
    __syncthreads();
    scn[t] = (t < 256) ? hist[t] : 0u;
    __syncthreads();
    for (int off = 1; off < 1024; off <<= 1) {
        unsigned v = (t + off < 1024) ? scn[t + off] : 0u;
        __syncthreads();
        scn[t] += v;
        __syncthreads();
    }
    {
        unsigned excl = (t < 1023) ? scn[t + 1] : 0u;
        if (excl < r2 && r2 <= scn[t]) { sT = (pref24 << 8) | (unsigned)t; sr3 = r2 - excl; }
    }
    if (t == 0) ntie = 0;
    __syncthreads();
    unsigned T = sT, r3 = sr3;

    // ---- phase 4a: per-thread weighted count of strictly-greater; ties ----
    unsigned mycnt = 0;
    for (int i = 0; i < 64; i++) {
        int idx = t + i * 1024;
        unsigned u = __float_as_uint(m[idx]);
        if (u > T && __uint_as_float(u) > MASK_THRESHOLD) mycnt++;
        if (u == T) {
            unsigned ti = atomicAdd(&ntie, 1u);
            if (ti < 64u) tiebuf[ti] = (unsigned)idx;
        }
    }
    scn[t] = mycnt;
    __syncthreads();
    for (int off = 1; off < 1024; off <<= 1) {           // inclusive prefix scan
        unsigned v = (t >= off) ? scn[t - off] : 0u;
        __syncthreads();
        scn[t] += v;
        __syncthreads();
    }
    unsigned base = scn[t] - mycnt;

    // ---- phase 4b: deterministic compaction + gather means ----
    unsigned pos = base;
    for (int i = 0; i < 64; i++) {
        int idx = t + i * 1024;
        unsigned u = __float_as_uint(m[idx]);
        if (u > T && __uint_as_float(u) > MASK_THRESHOLD) {
            const float* g = means + ((size_t)row * HW_N + idx) * 3;
            size_t o = (size_t)row * K_SEL + pos;
            sampX[o] = g[0]; sampY[o] = g[1]; sampZ[o] = g[2];
            pos++;
        }
    }
    __syncthreads();
    if (t == 0) {
        unsigned tot = scn[1023];
        unsigned nt = (ntie < 64u) ? ntie : 64u;
        // insertion-sort tie indices ascending (matches top_k stability)
        for (unsigned a = 1; a < nt; a++) {
            unsigned key = tiebuf[a];
            int b = (int)a - 1;
            while (b >= 0 && tiebuf[b] > key) { tiebuf[b + 1] = tiebuf[b]; b--; }
            tiebuf[b + 1] = key;
        }
        unsigned take = (r3 < nt) ? r3 : nt;
        if (__uint_as_float(T) > MASK_THRESHOLD) {
            for (unsigned a = 0; a < take; a++) {
                unsigned idx = tiebuf[a];
                const float* g = means + ((size_t)row * HW_N + idx) * 3;
                size_t o = (size_t)row * K_SEL + tot;
                sampX[o] = g[0]; sampY[o] = g[1]; sampZ[o] = g[2];
                tot++;
            }
        }
        cnt[row] = (int)tot;
    }
}

// ---------------------------------------------------------------------------
// Kernel C: NN distance. One block per (row, 256-sample chunk). Mesh in LDS.
// ---------------------------------------------------------------------------
__global__ void __launch_bounds__(256) dist_kernel(
    const float* __restrict__ meshX, const float* __restrict__ meshY,
    const float* __restrict__ meshZ,
    const float* __restrict__ sampX, const float* __restrict__ sampY,
    const float* __restrict__ sampZ,
    const int* __restrict__ cnt, float* __restrict__ partial)
{
    __shared__ float mx[NMESH], my[NMESH], mz[NMESH];
    __shared__ float red[256];
    int blk = blockIdx.x;
    int row = blk >> 2;
    int chunk = blk & 3;
    int t = threadIdx.x;

    for (int i = t; i < NMESH; i += 256) {
        int o = row * NMESH + i;
        mx[i] = meshX[o]; my[i] = meshY[o]; mz[i] = meshZ[o];
    }
    __syncthreads();

    int n = cnt[row];
    int j = chunk * 256 + t;
    float acc = 0.0f;
    if (j < n) {
        size_t o = (size_t)row * K_SEL + j;
        float sx = sampX[o], sy = sampY[o], sz = sampZ[o];
        float mind = 3.4e38f;
#pragma unroll 4
        for (int p = 0; p < NMESH; p++) {
            float dx = sx - mx[p], dy = sy - my[p], dz = sz - mz[p];
            float d2 = fmaf(dx, dx, fmaf(dy, dy, dz * dz));
            mind = fminf(mind, d2);
        }
        acc = mind;
    }
    red[t] = acc;
    __syncthreads();
    for (int off = 128; off > 0; off >>= 1) {
        if (t < off) red[t] += red[t + off];
        __syncthreads();
    }
    if (t == 0) partial[blk] = red[0];
}

// ---------------------------------------------------------------------------
// Kernel D: final deterministic reduce.
// ---------------------------------------------------------------------------
__global__ void __launch_bounds__(256) finish_kernel(
    const float* __restrict__ partial, const int* __restrict__ cnt,
    float* __restrict__ out)
{
    __shared__ double red[256];
    __shared__ int rc[64];
    int t = threadIdx.x;
    red[t] = (double)partial[t];
    if (t < 64) rc[t] = cnt[t];
    __syncthreads();
    for (int off = 128; off > 0; off >>= 1) {
        if (t < off) red[t] += red[t + off];
        __syncthreads();
    }
    for (int off = 32; off > 0; off >>= 1) {
        if (t < off) rc[t] += rc[t + off];
        __syncthreads();
    }
    if (t == 0) {
        float ns = fmaxf((float)rc[0], 1.0f);
        out[0] = (float)(red[0] / (double)ns);
    }
}

extern "C" void kernel_launch(void* const* d_in, const int* in_sizes, int n_in,
                              void* d_out, int out_size, void* d_ws, size_t ws_size,
                              hipStream_t stream) {
    const float* hp    = (const float*)d_in[0];
    const float* means = (const float*)d_in[1];
    const float* mask  = (const float*)d_in[2];
    const int*   hv    = (const int*)  d_in[3];
    const float* vtl   = (const float*)d_in[4];
    const float* vtr   = (const float*)d_in[5];
    const float* sdl   = (const float*)d_in[6];
    const float* sdr   = (const float*)d_in[7];
    const float* pdl   = (const float*)d_in[8];
    const float* pdr   = (const float*)d_in[9];
    float* out = (float*)d_out;

    float* ws = (float*)d_ws;
    float* meshX = ws;                         // 64*1556
    float* meshY = meshX + NROW * NMESH;
    float* meshZ = meshY + NROW * NMESH;
    float* sampX = meshZ + NROW * NMESH;       // 64*1024
    float* sampY = sampX + NROW * K_SEL;
    float* sampZ = sampY + NROW * K_SEL;
    float* partial = sampZ + NROW * K_SEL;     // 256
    int*   cnt = (int*)(partial + 256);        // 64

    mesh_kernel<<<NROW * 2, 256, 0, stream>>>(hp, hv, vtl, vtr, sdl, sdr, pdl, pdr,
                                              meshX, meshY, meshZ);
    topk_kernel<<<NROW, 1024, 0, stream>>>(mask, means, hv, sampX, sampY, sampZ, cnt);
    dist_kernel<<<NROW * 4, 256, 0, stream>>>(meshX, meshY, meshZ,
                                              sampX, sampY, sampZ, cnt, partial);
    finish_kernel<<<1, 256, 0, stream>>>(partial, cnt, out);
}